// Round 10
// baseline (299.090 us; speedup 1.0000x reference)
//
#include <hip/hip_runtime.h>
#include <hip/hip_bf16.h>

#define N_NODES 4096
#define N_EDGES 8192
#define NGRAPH  256
#define AFEAT   9
#define BFEAT   4
#define H       128
#define NL      3
#define KS      129              // k-slices including the e2_b bias slice
#define SPLITS  4                // x 2 o-halves = 8 = XCD count: bid&7 pins L2
#define TILE_E  64
#define NPB     4                // nodes per k_node block
#define SLICE_SH    16384        // shorts per k-slice (chunked layout)
#define SLICE_BYTES 32768        // bytes per k-slice

#define EMLP_BLOCKS (H * (N_EDGES / 256))   // 4096
#define ATOM_BLOCKS (N_NODES / 2)           // 2048
#define PREP_BLOCKS (NL * KS * 4)           // 1548

typedef short short8 __attribute__((ext_vector_type(8)));
typedef float f32x4 __attribute__((ext_vector_type(4)));

// ---- bf16 helpers (RNE, finite inputs) ----
__device__ __forceinline__ short f2b(float f){
    union { float f; unsigned u; } c; c.f = f;
    unsigned r = c.u + 0x7FFFu + ((c.u >> 16) & 1u);
    return (short)(r >> 16);
}
__device__ __forceinline__ float gelu_exact(float x){
    return 0.5f * x * (1.0f + erff(x * 0.70710678118654752440f));
}

// ---------- K_PRE: fused edge-MLP + atom-MLP + B-relayout (independent outputs) ----------
// bt layout: element B_k[i][o] at short offset
// (((o>>4)*4 + (i>>5))*64 + ((i>>3)&3)*16 + (o&15))*8 + (i&7) -- a wave's
// (o-tile t, ic) fragment = contiguous 1 KB line at (t*4+ic)*1024 + lane*16.
__global__ void k_fused_pre(const float* __restrict__ ea, const float* __restrict__ w1,
                            const float* __restrict__ b1, float* __restrict__ ehT,
                            const float* __restrict__ x, const float* __restrict__ aw,
                            const float* __restrict__ ab, float* __restrict__ h,
                            short* __restrict__ hb,
                            const float* __restrict__ e2w, const float* __restrict__ e2b,
                            short* __restrict__ bt){
    __shared__ float smem[H * 33];
    int bid = blockIdx.x, tid = threadIdx.x;

    if (bid < EMLP_BLOCKS){
        // ---- edge MLP: block = (one o) x (256 contiguous edges); all layers ----
        int o = bid >> 5;
        int e = (bid & 31) * 256 + tid;
        float4 a = *(const float4*)(ea + (size_t)e * BFEAT);
        #pragma unroll
        for (int l = 0; l < NL; ++l){
            float v = b1[l * H + o]
                    + a.x * w1[(l * BFEAT + 0) * H + o]
                    + a.y * w1[(l * BFEAT + 1) * H + o]
                    + a.z * w1[(l * BFEAT + 2) * H + o]
                    + a.w * w1[(l * BFEAT + 3) * H + o];
            v = gelu_exact(v);
            ehT[((size_t)l * KS + o) * N_EDGES + e] = v;
            if (o == 0) ehT[((size_t)l * KS + H) * N_EDGES + e] = 1.0f;   // bias slice
        }
    } else if (bid < EMLP_BLOCKS + ATOM_BLOCKS){
        // ---- atom MLP: 2 nodes per block ----
        int b = bid - EMLP_BLOCKS;
        int half = tid >> 7, o = tid & 127;
        int n = b * 2 + half;
        float* xs = smem + half * 16;
        if (o < AFEAT) xs[o] = x[n * AFEAT + o];
        __syncthreads();
        float a = ab[o];
        #pragma unroll
        for (int f = 0; f < AFEAT; ++f) a += xs[f] * aw[f * H + o];
        a = fmaxf(a, 0.0f);
        h[(size_t)n * H + o]  = a;
        hb[(size_t)n * H + o] = f2b(a);
    } else {
        // ---- B relayout ----
        int b  = bid - (EMLP_BLOCKS + ATOM_BLOCKS);
        int o0 = (b & 3) * 32;
        int k  = (b >> 2) % KS;
        int l  = (b >> 2) / KS;
        const float* src = (k < H) ? (e2w + ((size_t)l * H + k) * (H * H))
                                   : (e2b + (size_t)l * (H * H));
        for (int idx = tid; idx < H * 32; idx += 256){
            int i = idx >> 5, op = idx & 31;
            smem[i * 33 + op] = src[i * H + o0 + op];
        }
        __syncthreads();
        short* dst = bt + (size_t)(l * KS + k) * SLICE_SH;
        for (int idx = tid; idx < 32 * H; idx += 256){
            int j    = idx & 7;
            int quad = (idx >> 3) & 3;
            int op   = (idx >> 5) & 31;
            int ic   = idx >> 10;
            int i    = ic * 32 + quad * 8 + j;
            int o    = o0 + op;
            dst[((((o >> 4) * 4 + ic) * 64) + quad * 16 + (o & 15)) * 8 + j]
                = f2b(smem[i * 33 + op]);
        }
    }
}

// ---------- K_CSR: degree histogram + scan + CSR fill + molsum/cnt zero (one block) ----------
__global__ void k_csr(const int* __restrict__ ei, int* __restrict__ row_ptr,
                      int* __restrict__ eidx, float* __restrict__ molsum,
                      float* __restrict__ cnt){
    __shared__ int hist[N_NODES];
    __shared__ int part[256];
    int t = threadIdx.x;
    for (int i = t; i < N_NODES; i += 256) hist[i] = 0;
    for (int i = t; i < NGRAPH * H; i += 256) molsum[i] = 0.0f;
    for (int i = t; i < NGRAPH; i += 256) cnt[i] = 0.0f;
    __syncthreads();
    for (int e = t; e < N_EDGES; e += 256) atomicAdd(&hist[ei[N_EDGES + e]], 1);
    __syncthreads();
    int base = t * 16;
    int loc[16]; int s = 0;
    #pragma unroll
    for (int i = 0; i < 16; ++i){ loc[i] = s; s += hist[base + i]; }
    part[t] = s;
    __syncthreads();
    if (t == 0){
        int run = 0;
        for (int i = 0; i < 256; ++i){ int v = part[i]; part[i] = run; run += v; }
        row_ptr[N_NODES] = run;
    }
    __syncthreads();
    int off = part[t];
    #pragma unroll
    for (int i = 0; i < 16; ++i) row_ptr[base + i] = off + loc[i];
    __syncthreads();                       // everyone done reading hist
    #pragma unroll
    for (int i = 0; i < 16; ++i) hist[base + i] = off + loc[i];   // cursor
    __syncthreads();
    for (int e = t; e < N_EDGES; e += 256){
        int d = ei[N_EDGES + e];
        int pos = atomicAdd(&hist[d], 1);
        eidx[pos] = e;
    }
}

// ---------- K4: the big fused GEMM: parts[e][split][o] = sum_k eh[e,k]*(g[e] @ B_k) ----------
// Reg-streamed B, depth-2 X/Y/Z prefetch, XCD-pinned (so=bid&7), grid 1024
// = 4 blocks/CU. Unchanged from r9 except parts layout [e][split][o] for
// k_node gather locality. No barriers in the k-loop.
__global__ __launch_bounds__(256, 2)
void k_msg_gemm(const short* __restrict__ bt, const float* __restrict__ ehT,
                const short* __restrict__ hb, const int* __restrict__ ei,
                float* __restrict__ parts, int l){
    __shared__ __align__(16) float ehs[33 * TILE_E];

    const int tid  = threadIdx.x;
    const int lane = tid & 63, w = tid >> 6;   // 4 waves
    const int col  = lane & 15, quad = lane >> 4;

    const int so    = blockIdx.x & 7;          // XCD id on 8-XCD round-robin
    const int split = so & 3;
    const int ohalf = so >> 2;
    const int tile  = blockIdx.x >> 3;
    const int t     = ohalf * 4 + w;           // o-tile 0..7 (16 cols each)
    const int kbeg  = (KS * split) >> 2;
    const int kend  = (KS * (split + 1)) >> 2;
    const int kcnt  = kend - kbeg;             // 32 (33 for split 3)
    const int ebase = tile * TILE_E;

    // stage eh slice [kcnt][64] (f32) once, shared by the 4 waves
    for (int idx = tid; idx < kcnt * TILE_E; idx += 256){
        int kk = idx >> 6, e = idx & 63;
        ehs[idx] = ehT[((size_t)(l * KS + kbeg + kk)) * N_EDGES + ebase + e];
    }

    // load G fragments (A-operand, loop-invariant): gf[msub][ichunk]
    short8 gf[4][4];
    #pragma unroll
    for (int m = 0; m < 4; ++m){
        int e = ebase + m * 16 + col;
        int s = ei[e];
        const char* gb = (const char*)hb + ((size_t)s * H + quad * 8) * 2;
        #pragma unroll
        for (int ic = 0; ic < 4; ++ic)
            gf[m][ic] = *(const short8*)(gb + ic * 64);
    }

    float acc[4][4];
    #pragma unroll
    for (int m = 0; m < 4; ++m)
        #pragma unroll
        for (int r = 0; r < 4; ++r) acc[m][r] = 0.0f;

    // per-lane base into this wave's o-tile of the B stream
    const char* bsrc = (const char*)bt + (size_t)(l * KS + kbeg) * SLICE_BYTES
                     + t * 4096 + lane * 16;

    short8 X[4], Y[4], Z[4];

    auto loadB = [&](short8 (&B)[4], int kk){
        const char* p = bsrc + (size_t)kk * SLICE_BYTES;
        #pragma unroll
        for (int ic = 0; ic < 4; ++ic)
            B[ic] = *(const short8*)(p + ic * 1024);
    };
    auto computeB = [&](const short8 (&B)[4], int kk){
        __builtin_amdgcn_s_setprio(1);
        #pragma unroll
        for (int m = 0; m < 4; ++m){
            f32x4 ev = *(const f32x4*)(ehs + kk * TILE_E + m * 16 + quad * 4);
            f32x4 U = {0.0f, 0.0f, 0.0f, 0.0f};
            #pragma unroll
            for (int ic = 0; ic < 4; ++ic)
                U = __builtin_amdgcn_mfma_f32_16x16x32_bf16(gf[m][ic], B[ic], U, 0, 0, 0);
            #pragma unroll
            for (int r = 0; r < 4; ++r)
                acc[m][r] += ev[r] * U[r];
        }
        __builtin_amdgcn_s_setprio(0);
    };

    loadB(X, 0); loadB(Y, 1); loadB(Z, 2);     // kcnt >= 32 always
    __syncthreads();   // ehs visible (one-time)

    int kk = 0;
    for (; kk + 3 < kcnt; kk += 3){
        computeB(X, kk);     loadB(X, kk + 3);
        computeB(Y, kk + 1); if (kk + 4 < kcnt) loadB(Y, kk + 4);
        computeB(Z, kk + 2); if (kk + 5 < kcnt) loadB(Z, kk + 5);
    }
    // kcnt - kk in {1,2,3}; buffers already loaded
    computeB(X, kk);
    if (kk + 1 < kcnt) computeB(Y, kk + 1);
    if (kk + 2 < kcnt) computeB(Z, kk + 2);

    // epilogue: parts[e][split][o] (wave-exclusive 16 cols)
    float* pb = parts + ((size_t)ebase * SPLITS + split) * H + t * 16;
    #pragma unroll
    for (int m = 0; m < 4; ++m)
        #pragma unroll
        for (int r = 0; r < 4; ++r){
            int row = m * 16 + quad * 4 + r;
            pb[(size_t)row * SPLITS * H + col] = acc[m][r];
        }
}

// ---------- K5: node update, 4 nodes/block, fused pool on last layer ----------
__global__ void k_node(const float* __restrict__ parts, const int* __restrict__ eidx,
                       const int* __restrict__ row_ptr,
                       const float* __restrict__ rw, const float* __restrict__ cb,
                       const float* __restrict__ lg, const float* __restrict__ lb,
                       float* __restrict__ h, short* __restrict__ hb,
                       const int* __restrict__ batch, float* __restrict__ molsum,
                       float* __restrict__ cnt, int l, int dolast){
    __shared__ float hs[NPB][H];
    __shared__ float red[NPB][2][2];           // [node][sum/sq][wavehalf]
    int n0 = blockIdx.x * NPB, o = threadIdx.x;
    const float* W = rw + (size_t)l * H * H;

    float hv[NPB], root[NPB], a[NPB];
    #pragma unroll
    for (int m = 0; m < NPB; ++m){
        hv[m] = h[(size_t)(n0 + m) * H + o];
        hs[m][o] = hv[m];
        root[m] = cb[l * H + o];
    }
    __syncthreads();

    // CSR gather of split partials: parts[e][split][o] -> 2 KB contiguous/edge
    #pragma unroll
    for (int m = 0; m < NPB; ++m){
        int p0 = row_ptr[n0 + m], p1 = row_ptr[n0 + m + 1];
        float s = 0.0f;
        for (int p = p0; p < p1; ++p){
            const float* pr = parts + (size_t)eidx[p] * SPLITS * H + o;
            #pragma unroll
            for (int sp = 0; sp < SPLITS; ++sp) s += pr[sp * H];
        }
        int d = p1 - p0;
        a[m] = s / (float)(d > 0 ? d : 1);
    }

    // root transform: one W read serves 4 nodes
    #pragma unroll 8
    for (int i = 0; i < H; ++i){
        float wv = W[i * H + o];
        #pragma unroll
        for (int m = 0; m < NPB; ++m) root[m] += hs[m][i] * wv;
    }

    float v[NPB];
    #pragma unroll
    for (int m = 0; m < NPB; ++m){
        float hn = fmaxf(a[m] + root[m], 0.0f);
        v[m] = hv[m] + hn;
        float s = v[m], q = v[m] * v[m];
        #pragma unroll
        for (int off = 32; off > 0; off >>= 1){
            s += __shfl_down(s, off, 64);
            q += __shfl_down(q, off, 64);
        }
        if ((o & 63) == 0){ red[m][0][o >> 6] = s; red[m][1][o >> 6] = q; }
    }
    __syncthreads();
    #pragma unroll
    for (int m = 0; m < NPB; ++m){
        float S = red[m][0][0] + red[m][0][1];
        float Q = red[m][1][0] + red[m][1][1];
        float mean = S * (1.0f / H);
        float var  = Q * (1.0f / H) - mean * mean;
        float out  = (v[m] - mean) * rsqrtf(var + 1e-5f) * lg[l * H + o] + lb[l * H + o];
        int n = n0 + m;
        h[(size_t)n * H + o]  = out;
        hb[(size_t)n * H + o] = f2b(out);
        if (dolast){
            int b = batch[n];
            atomicAdd(&molsum[b * H + o], out);
            if (o == 0) atomicAdd(&cnt[b], 1.0f);
        }
    }
}

// ---------- K7: head MLP ----------
__global__ void k_head(const float* __restrict__ molsum, const float* __restrict__ cnt,
                       const float* __restrict__ w1, const float* __restrict__ b1,
                       const float* __restrict__ w2, const float* __restrict__ b2,
                       float* __restrict__ out){
    __shared__ float mol[H];
    int g = blockIdx.x, t = threadIdx.x;   // 64 threads = 1 wave
    float c = fmaxf(cnt[g], 1.0f);
    mol[t]      = molsum[g * H + t] / c;
    mol[t + 64] = molsum[g * H + t + 64] / c;
    __syncthreads();
    float a = b1[t];
    #pragma unroll 8
    for (int i = 0; i < H; ++i) a += mol[i] * w1[i * 64 + t];
    float hid = gelu_exact(a);
    float p = hid * w2[t];
    #pragma unroll
    for (int off = 32; off > 0; off >>= 1) p += __shfl_down(p, off, 64);
    if (t == 0) out[g] = p + b2[0];
}

extern "C" void kernel_launch(void* const* d_in, const int* in_sizes, int n_in,
                              void* d_out, int out_size, void* d_ws, size_t ws_size,
                              hipStream_t stream){
    (void)in_sizes; (void)n_in; (void)out_size; (void)ws_size;
    const float* x     = (const float*)d_in[0];
    const int*   ei    = (const int*)  d_in[1];
    const float* ea    = (const float*)d_in[2];
    const int*   batch = (const int*)  d_in[3];
    const float* aw    = (const float*)d_in[4];
    const float* ab    = (const float*)d_in[5];
    const float* e1w   = (const float*)d_in[6];
    const float* e1b   = (const float*)d_in[7];
    const float* e2w   = (const float*)d_in[8];
    const float* e2b   = (const float*)d_in[9];
    const float* rw    = (const float*)d_in[10];
    const float* cb    = (const float*)d_in[11];
    const float* lg    = (const float*)d_in[12];
    const float* lb    = (const float*)d_in[13];
    const float* hw1   = (const float*)d_in[14];
    const float* hb1   = (const float*)d_in[15];
    const float* hw2   = (const float*)d_in[16];
    const float* hb2   = (const float*)d_in[17];
    float* out = (float*)d_out;

    char* p = (char*)d_ws;
    auto carve = [&](size_t bytes){ char* r = p; p += (bytes + 255) & ~(size_t)255; return r; };
    short* bt     = (short*)carve((size_t)NL * KS * SLICE_SH * 2);    // 12.7 MB
    float* h      = (float*)carve((size_t)N_NODES * H * 4);           // 2 MB
    short* hbuf   = (short*)carve((size_t)N_NODES * H * 2);           // 1 MB
    float* ehT    = (float*)carve((size_t)NL * KS * N_EDGES * 4);     // 12.7 MB
    float* parts  = (float*)carve((size_t)N_EDGES * SPLITS * H * 4);  // 16.7 MB
    int*   row_ptr= (int*)  carve((size_t)(N_NODES + 1) * 4);
    int*   eidx   = (int*)  carve((size_t)N_EDGES * 4);
    float* molsum = (float*)carve((size_t)NGRAPH * H * 4);
    float* cnt    = (float*)carve((size_t)NGRAPH * 4);

    k_fused_pre<<<EMLP_BLOCKS + ATOM_BLOCKS + PREP_BLOCKS, 256, 0, stream>>>(
        ea, e1w, e1b, ehT, x, aw, ab, h, hbuf, e2w, e2b, bt);
    k_csr<<<1, 256, 0, stream>>>(ei, row_ptr, eidx, molsum, cnt);

    for (int l = 0; l < NL; ++l){
        k_msg_gemm<<<(N_EDGES / TILE_E) * 8, 256, 0, stream>>>(bt, ehT, hbuf, ei, parts, l);
        k_node<<<N_NODES / NPB, H, 0, stream>>>(parts, eidx, row_ptr, rw, cb, lg, lb,
                                                h, hbuf, batch, molsum, cnt, l,
                                                l == NL - 1 ? 1 : 0);
    }
    k_head<<<NGRAPH, 64, 0, stream>>>(molsum, cnt, hw1, hb1, hw2, hb2, out);
}